// Round 7
// baseline (442.137 us; speedup 1.0000x reference)
//
#include <hip/hip_runtime.h>
#include <hip/hip_bf16.h>
#include <math.h>
#include <stdint.h>

#define B_ 2
#define S_ 2048
#define E_ 2048
#define H_ 16
#define NOPE_ 64
#define ROPE_ 32
#define V_ 64
#define KVR_ 256
#define QKD_ 96
#define SCALE_ 0.10206207261596577f  /* 96^-0.5 */

typedef __hip_bfloat16 bf16;
typedef __attribute__((ext_vector_type(8))) short short8;
typedef __attribute__((ext_vector_type(4))) short short4v;
typedef __attribute__((ext_vector_type(4))) float floatx4;

__device__ __forceinline__ float bf2f(bf16 v) { return __bfloat162float(v); }
__device__ __forceinline__ float s2f(short v) {
    bf16 h = *reinterpret_cast<bf16*>(&v);
    return __bfloat162float(h);
}
__device__ __forceinline__ short f2bf_s(float f) {
    bf16 h = __float2bfloat16(f);
    return *reinterpret_cast<short*>(&h);
}
__device__ __forceinline__ void store_c(float* C, size_t i, float v) { C[i] = v; }
__device__ __forceinline__ void store_c(bf16* C, size_t i, float v) { C[i] = __float2bfloat16(v); }

// async 16B global -> LDS (proper addrspacecasts; no integer truncation)
__device__ __forceinline__ void g2l16(const bf16* g, bf16* l) {
    __builtin_amdgcn_global_load_lds(
        (const __attribute__((address_space(1))) void*)g,
        (__attribute__((address_space(3))) void*)l,
        16, 0, 0);
}

#if __has_builtin(__builtin_amdgcn_mfma_f32_16x16x16_bf16)
#define HAVE_M16 1
#define MFMA16(a, b, c) __builtin_amdgcn_mfma_f32_16x16x16_bf16(a, b, c, 0, 0, 0)
#elif __has_builtin(__builtin_amdgcn_mfma_f32_16x16x16bf16_1k)
#define HAVE_M16 1
#define MFMA16(a, b, c) __builtin_amdgcn_mfma_f32_16x16x16bf16_1k(a, b, c, 0, 0, 0)
#else
#define HAVE_M16 0
#endif

// ---------------- fp32 -> bf16 conversion ----------------
__global__ __launch_bounds__(256) void conv_bf16_kernel(const float* __restrict__ src,
                                                        bf16* __restrict__ dst, int n8) {
    int i = blockIdx.x * 256 + threadIdx.x;
    if (i >= n8) return;
    float4 a = ((const float4*)src)[2 * i];
    float4 b = ((const float4*)src)[2 * i + 1];
    short8 r;
    r[0] = f2bf_s(a.x); r[1] = f2bf_s(a.y); r[2] = f2bf_s(a.z); r[3] = f2bf_s(a.w);
    r[4] = f2bf_s(b.x); r[5] = f2bf_s(b.y); r[6] = f2bf_s(b.z); r[7] = f2bf_s(b.w);
    ((short8*)dst)[i] = r;
}

// ---------------- wkv_a (288x2048) -> zero-padded bf16 (384x2048) ----------------
__global__ __launch_bounds__(256) void conv_pad_wkva_kernel(const float* __restrict__ src,
                                                            bf16* __restrict__ dst) {
    int i = blockIdx.x * 256 + threadIdx.x;
    if (i >= 384 * 2048 / 8) return;
    int row = i >> 8;
    short8 r;
    if (row < 288) {
        float4 a = ((const float4*)src)[2 * i];
        float4 b = ((const float4*)src)[2 * i + 1];
        r[0] = f2bf_s(a.x); r[1] = f2bf_s(a.y); r[2] = f2bf_s(a.z); r[3] = f2bf_s(a.w);
        r[4] = f2bf_s(b.x); r[5] = f2bf_s(b.y); r[6] = f2bf_s(b.z); r[7] = f2bf_s(b.w);
    } else {
        for (int j = 0; j < 8; ++j) r[j] = 0;
    }
    ((short8*)dst)[i] = r;
}

// ---------------- wkvbT[h][c][d] = bf16(wkv_b[h*128+d][c]), d<64 ----------------
__global__ __launch_bounds__(256) void transpose_wkvbT_kernel(const float* __restrict__ wkv_b,
                                                              bf16* __restrict__ wkvbT) {
    int h = blockIdx.x, c = threadIdx.x;
#pragma unroll
    for (int d0 = 0; d0 < 64; d0 += 8) {
        short8 v;
#pragma unroll
        for (int j = 0; j < 8; ++j) v[j] = f2bf_s(wkv_b[(size_t)(h * 128 + d0 + j) * 256 + c]);
        *(short8*)(void*)&wkvbT[((size_t)h * 256 + c) * 64 + d0] = v;
    }
}

// ---------------- bf16 MFMA GEMM (m97-style): C(M,N) = A(M,K) @ B(N,K)^T ----------------
template <typename TC>
__global__ __launch_bounds__(256, 2) void gemm_bt_lds(const bf16* __restrict__ A,
                                                      const bf16* __restrict__ Bm,
                                                      TC* __restrict__ C,
                                                      int M, int N, int K) {
    __shared__ bf16 Asf[128 * 32];
    __shared__ bf16 Bsf[128 * 32];
    int tid = threadIdx.x;
    int lane = tid & 63, w = tid >> 6;
    int q4 = lane >> 4, c16 = lane & 15;
    int wr = w >> 1, wc = w & 1;
    int m0 = blockIdx.y * 128, n0 = blockIdx.x * 128;
    floatx4 acc[4][4];
#pragma unroll
    for (int mi = 0; mi < 4; ++mi)
#pragma unroll
        for (int ni = 0; ni < 4; ++ni) acc[mi][ni] = (floatx4){0.f, 0.f, 0.f, 0.f};

    for (int k0 = 0; k0 < K; k0 += 32) {
        __syncthreads();
#pragma unroll
        for (int i = 0; i < 2; ++i) {
            int c = (w << 6) + lane + i * 256;
            int row = c >> 2, kc = c & 3;
            g2l16(&A[(size_t)(m0 + row) * K + k0 + kc * 8], &Asf[c * 8]);
            g2l16(&Bm[(size_t)(n0 + row) * K + k0 + kc * 8], &Bsf[c * 8]);
        }
        __syncthreads();
        short8 af[4], bfr[4];
#pragma unroll
        for (int mi = 0; mi < 4; ++mi)
            af[mi] = *(const short8*)(const void*)&Asf[(wr * 64 + mi * 16 + c16) * 32 + q4 * 8];
#pragma unroll
        for (int ni = 0; ni < 4; ++ni)
            bfr[ni] = *(const short8*)(const void*)&Bsf[(wc * 64 + ni * 16 + c16) * 32 + q4 * 8];
#pragma unroll
        for (int mi = 0; mi < 4; ++mi)
#pragma unroll
            for (int ni = 0; ni < 4; ++ni)
                acc[mi][ni] = __builtin_amdgcn_mfma_f32_16x16x32_bf16(af[mi], bfr[ni], acc[mi][ni], 0, 0, 0);
    }
#pragma unroll
    for (int mi = 0; mi < 4; ++mi)
#pragma unroll
        for (int ni = 0; ni < 4; ++ni)
#pragma unroll
            for (int r = 0; r < 4; ++r) {
                int row = m0 + wr * 64 + mi * 16 + q4 * 4 + r;
                int col = n0 + wc * 64 + ni * 16 + c16;
                store_c(C, (size_t)row * N + col, acc[mi][ni][r]);
            }
}

// ---------------- small batched bf16 MFMA GEMM (64x64 tiles, global_load_lds) -------------
template <typename TC>
__global__ __launch_bounds__(256, 4) void gemm64_lds(const bf16* __restrict__ A, int lda, int aoffz,
                                                     const bf16* __restrict__ Bm, int ldb, int boffz,
                                                     TC* __restrict__ C, int ldc, int coffz,
                                                     int K, float scale) {
    int z = blockIdx.z;
    A += (size_t)z * aoffz;
    Bm += (size_t)z * boffz;
    C += (size_t)z * coffz;
    __shared__ bf16 Asf[64 * 32];
    __shared__ bf16 Bsf[64 * 32];
    int tid = threadIdx.x;
    int lane = tid & 63, w = tid >> 6;
    int q4 = lane >> 4, c16 = lane & 15;
    int m0 = blockIdx.y * 64, n0 = blockIdx.x * 64;
    floatx4 acc[4];
#pragma unroll
    for (int ni = 0; ni < 4; ++ni) acc[ni] = (floatx4){0.f, 0.f, 0.f, 0.f};
    int row = tid >> 2, kc = tid & 3;
    for (int k0 = 0; k0 < K; k0 += 32) {
        __syncthreads();
        g2l16(&A[(size_t)(m0 + row) * lda + k0 + kc * 8], &Asf[tid * 8]);
        g2l16(&Bm[(size_t)(n0 + row) * ldb + k0 + kc * 8], &Bsf[tid * 8]);
        __syncthreads();
        short8 af = *(const short8*)(const void*)&Asf[(w * 16 + c16) * 32 + q4 * 8];
#pragma unroll
        for (int ni = 0; ni < 4; ++ni) {
            short8 bfr = *(const short8*)(const void*)&Bsf[(ni * 16 + c16) * 32 + q4 * 8];
            acc[ni] = __builtin_amdgcn_mfma_f32_16x16x32_bf16(af, bfr, acc[ni], 0, 0, 0);
        }
    }
#pragma unroll
    for (int ni = 0; ni < 4; ++ni)
#pragma unroll
        for (int rr = 0; rr < 4; ++rr)
            store_c(C, (size_t)(m0 + w * 16 + q4 * 4 + rr) * ldc + n0 + ni * 16 + c16,
                    acc[ni][rr] * scale);
}

// ---------------- LayerNorm(kv_c) + RoPE(k_pe); input stride 384 ----------------
__global__ __launch_bounds__(256) void ln_rope_kernel(const float* __restrict__ kvraw,
                                                      const float* __restrict__ g,
                                                      const float* __restrict__ bta,
                                                      float* __restrict__ kv_c,
                                                      float* __restrict__ kpe) {
    int r = blockIdx.x;
    int tid = threadIdx.x;
    int lane = tid & 63, w = tid >> 6;
    float x = kvraw[(size_t)r * 384 + tid];
    float v1 = x, v2 = x * x;
#pragma unroll
    for (int o = 32; o; o >>= 1) { v1 += __shfl_down(v1, o); v2 += __shfl_down(v2, o); }
    __shared__ float s1[4], s2[4], stats[2];
    if (lane == 0) { s1[w] = v1; s2[w] = v2; }
    __syncthreads();
    if (tid == 0) {
        float S1 = s1[0] + s1[1] + s1[2] + s1[3];
        float S2 = s2[0] + s2[1] + s2[2] + s2[3];
        float mean = S1 / 256.0f;
        float var = S2 / 256.0f - mean * mean;
        stats[0] = mean;
        stats[1] = rsqrtf(var + 1e-5f);
    }
    __syncthreads();
    float y = (x - stats[0]) * stats[1] * g[tid] + bta[tid];
    kv_c[(size_t)r * 256 + tid] = y;
    if (tid < 16) {
        int j = tid;
        int s = r & (S_ - 1);
        float freq = expf(-(float)(2 * j) * 0.28782313662425572f);  // ln(1e4)/32
        float ang = (float)s * freq;
        float c = cosf(ang), sn = sinf(ang);
        float x0 = kvraw[(size_t)r * 384 + 256 + 2 * j];
        float x1 = kvraw[(size_t)r * 384 + 256 + 2 * j + 1];
        kpe[(size_t)r * 32 + 2 * j]     = x0 * c - x1 * sn;
        kpe[(size_t)r * 32 + 2 * j + 1] = x0 * sn + x1 * c;
    }
}

// ---------------- C2 / P2 ----------------
__global__ __launch_bounds__(64) void c2p2_kernel(const float* __restrict__ fcw_c,
                                                  const float* __restrict__ fcb_c,
                                                  const float* __restrict__ fcw_p,
                                                  const float* __restrict__ fcb_p,
                                                  float* __restrict__ C2,
                                                  float* __restrict__ P2) {
    int t = blockIdx.x;
    int k = threadIdx.x;
    __shared__ float Crow[256], Prow[256];
    for (int i = k; i < 128; i += 64) {
        float div = expf(-(float)i * 0.07195578415606393f);  // ln(1e4)/128
        float ap = (float)t * div;
        Prow[2 * i]     = sinf(ap);
        Prow[2 * i + 1] = cosf(ap);
        float ac = (float)(t >> 1) * div;
        Crow[2 * i]     = sinf(ac);
        Crow[2 * i + 1] = cosf(ac);
    }
    __syncthreads();
    float sc = fcb_c[k], sp = fcb_p[k];
    for (int c = 0; c < 256; ++c) {
        sc += Crow[c] * fcw_c[(size_t)k * 256 + c];
        sp += Prow[c] * fcw_p[(size_t)k * 256 + c];
    }
    C2[(size_t)t * 64 + k] = sc;
    P2[(size_t)t * 64 + k] = sp;
}

__global__ __launch_bounds__(256) void gates_kernel(const float* __restrict__ C2,
                                                    const float* __restrict__ P2,
                                                    float* __restrict__ g0,
                                                    float* __restrict__ g1) {
    int t = blockIdx.x * 256 + threadIdx.x;
    if (t >= S_) return;
    float d0 = 0.f;
    for (int k = 0; k < 64; ++k) d0 += C2[(size_t)t * 64 + k] * P2[(size_t)t * 64 + k];
    g0[t] = 1.0f / (1.0f + expf(-d0));
    float gg = 0.f;
    if (t & 1) {
        float d1 = 0.f;
        for (int k = 0; k < 64; ++k) d1 += C2[(size_t)t * 64 + k] * P2[(size_t)(t - 1) * 64 + k];
        gg = 1.0f / (1.0f + expf(-d1));
    }
    g1[t] = gg;
}

// ---------------- gated kv_t -> kve_full [B*S][288] + packed odd kvo [B][1024][296] ------
__global__ __launch_bounds__(256) void kve_kernel(const float* __restrict__ kv_c,
                                                  const float* __restrict__ kpe,
                                                  const float* __restrict__ g0,
                                                  const float* __restrict__ g1,
                                                  bf16* __restrict__ kve_full,
                                                  bf16* __restrict__ kvo) {
    int r = blockIdx.x, tid = threadIdx.x;
    int b = r >> 11, t = r & (S_ - 1);
    float a = g0[t], bb = g1[t];
    float v = a * kv_c[(size_t)r * 256 + tid];
    if (t & 1) v += bb * kv_c[(size_t)(r - 1) * 256 + tid];
    bf16 vb = __float2bfloat16(v);
    kve_full[(size_t)r * 288 + tid] = vb;
    if (t & 1) kvo[((size_t)b * 1024 + (t >> 1)) * 296 + tid] = vb;
    if (tid < 32) {
        float u = a * kpe[(size_t)r * 32 + tid];
        if (t & 1) u += bb * kpe[(size_t)(r - 1) * 32 + tid];
        bf16 ub = __float2bfloat16(u);
        kve_full[(size_t)r * 288 + 256 + tid] = ub;
        if (t & 1) kvo[((size_t)b * 1024 + (t >> 1)) * 296 + 256 + tid] = ub;
    }
}

// ---------------- kvoT[b][uch][c][16] = kvo[b][uch*16+j][c] ----------------
__global__ __launch_bounds__(256) void kvoT2_kernel(const bf16* __restrict__ kvo,
                                                    bf16* __restrict__ kvoT) {
    int uch = blockIdx.x, b = blockIdx.y;
    int c = threadIdx.x;
    const bf16* src = kvo + ((size_t)b * 1024 + uch * 16) * 296 + c;
    short8 o0, o1;
#pragma unroll
    for (int j = 0; j < 8; ++j) o0[j] = *(const short*)&src[(size_t)j * 296];
#pragma unroll
    for (int j = 0; j < 8; ++j) o1[j] = *(const short*)&src[(size_t)(8 + j) * 296];
    bf16* dst = kvoT + (((size_t)b * 64 + uch) * 256 + c) * 16;
    *(short8*)(void*)dst = o0;
    *(short8*)(void*)(dst + 8) = o1;
}

// ---------------- roped, scaled q_pe -> qe[...,256:288) ----------------
__global__ __launch_bounds__(256) void rope_qe_kernel(const bf16* __restrict__ q,
                                                      bf16* __restrict__ qe) {
    int idx = blockIdx.x * 256 + threadIdx.x;
    if (idx >= B_ * S_ * H_ * 16) return;
    int j = idx & 15;
    int s = (idx >> 8) & (S_ - 1);
    float freq = expf(-(float)(2 * j) * 0.28782313662425572f);
    float ang = (float)s * freq;
    float c = cosf(ang), sn = sinf(ang);
    size_t row = idx >> 4;
    float a0 = bf2f(q[row * QKD_ + NOPE_ + 2 * j]);
    float a1 = bf2f(q[row * QKD_ + NOPE_ + 2 * j + 1]);
    qe[row * 288 + 256 + 2 * j]     = __float2bfloat16((a0 * c - a1 * sn) * SCALE_);
    qe[row * 288 + 256 + 2 * j + 1] = __float2bfloat16((a0 * sn + a1 * c) * SCALE_);
}

// ---------------- transposed-score flash attention (v4) ----------------
// block = (b, 4 consecutive s); wave w owns s0+w. Scores D[u][h] via MFMA from LDS;
// PV A-operand streamed directly from global (coalesced, L2-resident); self-score fused.
__global__ __launch_bounds__(256, 3) void attn4_kernel(const bf16* __restrict__ qe,
                                                       const bf16* __restrict__ kvo,
                                                       const bf16* __restrict__ kvoT,
                                                       const bf16* __restrict__ kve_full,
                                                       bf16* __restrict__ xout) {
    int s0 = (int)(gridDim.x - 1 - blockIdx.x) * 4;  // biggest blocks first
    int b = blockIdx.y;
    int tid = threadIdx.x;
    int lane = tid & 63, w = tid >> 6;
    int q4 = lane >> 4, c16 = lane & 15;
    int s = s0 + w;
    int Nodd = (s + 1) >> 1;
    int NoddMax = (s0 + 4) >> 1;
    int niterB = (NoddMax + 15) >> 4;

    __shared__ bf16 kvos[2][16][296];   // score tiles; 592B rows, 16B-aligned stores
    __shared__ bf16 selfr[4][288];      // full self-key rows (kv 256 + kpe 32)

    const bf16* kvob = kvo + (size_t)b * 1024 * 296;
    const bf16* kvoTb = kvoT + (size_t)b * 64 * 4096;

    if (tid < 144) {
        int rr = tid >> 5, ch = tid & 31;   // rows 0..4 (144/32=4.5 -> rr<=4 guarded)
        if (rr < 4) {
            *(short8*)(void*)&selfr[rr][ch * 8] =
                *(const short8*)(const void*)&kve_full[(size_t)(b * S_ + s0 + rr) * 288 + ch * 8];
        } else {
            // rr==4: remaining 16 threads load chunk 32..35 of rows 0..3
            int r2 = (tid - 128) >> 2, c2 = 32 + ((tid - 128) & 3);
            *(short8*)(void*)&selfr[r2][c2 * 8] =
                *(const short8*)(const void*)&kve_full[(size_t)(b * S_ + s0 + r2) * 288 + c2 * 8];
        }
    }

    short8 qf[9];
    const bf16* qrow = qe + ((size_t)(b * S_ + s) * H_ + c16) * 288;
#pragma unroll
    for (int kk = 0; kk < 9; ++kk) qf[kk] = *(const short8*)(const void*)&qrow[kk * 32 + q4 * 8];

    floatx4 acc[16];
#pragma unroll
    for (int n = 0; n < 16; ++n) acc[n] = (floatx4){0.f, 0.f, 0.f, 0.f};
    float m_i = -1e30f, l_i = 0.f;

    short8 ra[3];
    auto load_regs = [&](int t) {
        const short8* sa = (const short8*)(const void*)(kvob + (size_t)t * 16 * 296);
#pragma unroll
        for (int i = 0; i < 3; ++i) {
            int idx = tid + i * 256;
            if (idx < 592) ra[i] = sa[idx];
        }
    };
    auto write_lds = [&](int p) {
        short8* da = (short8*)(void*)&kvos[p][0][0];
#pragma unroll
        for (int i = 0; i < 3; ++i) {
            int idx = tid + i * 256;
            if (idx < 592) da[idx] = ra[i];
        }
    };

    load_regs(0);
    write_lds(0);
    if (niterB > 1) load_regs(1);
    __syncthreads();

    for (int it = 0; it < niterB; ++it) {
        int p = it & 1;
        if (it + 1 < niterB) {
            write_lds(1 - p);
            if (it + 2 < niterB) load_regs(it + 2);
        }
        int u0 = it * 16;
        // scores^T: D[u][h], A = kvos rows (m=u), B = qf (n=h)
        floatx4 cf = (floatx4){0.f, 0.f, 0.f, 0.f};
#pragma unroll
        for (int kk = 0; kk < 9; ++kk) {
            short8 av = *(const short8*)(const void*)&kvos[p][c16][kk * 32 + q4 * 8];
            cf = __builtin_amdgcn_mfma_f32_16x16x32_bf16(av, qf[kk], cf, 0, 0, 0);
        }
        // PV A-operand: stream from global (coalesced 512B per instruction, L2-hot).
        // Issue early so latency overlaps the softmax VALU below.
        short4v a4[16];
        const bf16* pvb = kvoTb + (size_t)it * 4096 + q4 * 4;
#pragma unroll
        for (int n = 0; n < 16; ++n)
            a4[n] = *(const short4v*)(const void*)&pvb[(n * 16 + c16) * 16];

        int ub = u0 + q4 * 4;
#pragma unroll
        for (int r = 0; r < 4; ++r)
            if (ub + r >= Nodd) cf[r] = -1e30f;
        float tmax = fmaxf(fmaxf(cf[0], cf[1]), fmaxf(cf[2], cf[3]));
        tmax = fmaxf(tmax, __shfl_xor(tmax, 16));
        tmax = fmaxf(tmax, __shfl_xor(tmax, 32));
        float mn = fmaxf(m_i, tmax);
        bool chg = mn > m_i;
        float al = __expf(m_i - mn);
        float p0 = __expf(cf[0] - mn), p1 = __expf(cf[1] - mn);
        float p2 = __expf(cf[2] - mn), p3 = __expf(cf[3] - mn);
        float rs = p0 + p1 + p2 + p3;
        rs += __shfl_xor(rs, 16);
        rs += __shfl_xor(rs, 32);
        l_i = l_i * al + rs;
        m_i = mn;
        if (__any(chg)) {
#pragma unroll
            for (int n = 0; n < 16; ++n) {
                acc[n][0] *= al; acc[n][1] *= al; acc[n][2] *= al; acc[n][3] *= al;
            }
        }
#if HAVE_M16
        short4v pfv;
        pfv[0] = f2bf_s(p0); pfv[1] = f2bf_s(p1); pfv[2] = f2bf_s(p2); pfv[3] = f2bf_s(p3);
#pragma unroll
        for (int n = 0; n < 16; ++n) acc[n] = MFMA16(a4[n], pfv, acc[n]);
#else
        short8 pf;
        pf[0] = f2bf_s(p0); pf[1] = f2bf_s(p1); pf[2] = f2bf_s(p2); pf[3] = f2bf_s(p3);
        pf[4] = 0; pf[5] = 0; pf[6] = 0; pf[7] = 0;
#pragma unroll
        for (int n = 0; n < 16; ++n) {
            short8 af;
            af[0] = a4[n][0]; af[1] = a4[n][1]; af[2] = a4[n][2]; af[3] = a4[n][3];
            af[4] = 0; af[5] = 0; af[6] = 0; af[7] = 0;
            acc[n] = __builtin_amdgcn_mfma_f32_16x16x32_bf16(af, pf, acc[n], 0, 0, 0);
        }
#endif
        __syncthreads();
    }

    // self key (even s; odd s already included in odd set). Fused self-score:
    // dot(qf, selfr[w]) reduced over q4 -> score for head c16.
    if ((s & 1) == 0) {
        float d = 0.f;
#pragma unroll
        for (int kk = 0; kk < 9; ++kk)
#pragma unroll
            for (int j = 0; j < 8; ++j)
                d += s2f(qf[kk][j]) * bf2f(selfr[w][kk * 32 + q4 * 8 + j]);
        d += __shfl_xor(d, 16);
        d += __shfl_xor(d, 32);
        float mn = fmaxf(m_i, d);
        float al = __expf(m_i - mn);
        float pp = __expf(d - mn);
        l_i = l_i * al + pp;
        m_i = mn;
#pragma unroll
        for (int n = 0; n < 16; ++n) {
            short4v kv4 = *(const short4v*)(const void*)&selfr[w][n * 16 + q4 * 4];
#pragma unroll
            for (int r = 0; r < 4; ++r)
                acc[n][r] = acc[n][r] * al + pp * s2f(kv4[r]);
        }
    }

    float invl = 1.0f / l_i;
    bf16* orow = xout + ((size_t)(b * S_ + s) * H_ + c16) * 256;
#pragma unroll
    for (int n = 0; n < 16; ++n) {
        short4v o;
        o[0] = f2bf_s(acc[n][0] * invl);
        o[1] = f2bf_s(acc[n][1] * invl);
        o[2] = f2bf_s(acc[n][2] * invl);
        o[3] = f2bf_s(acc[n][3] * invl);
        *(short4v*)(void*)&orow[n * 16 + q4 * 4] = o;
    }
}

extern "C" void kernel_launch(void* const* d_in, const int* in_sizes, int n_in,
                              void* d_out, int out_size, void* d_ws, size_t ws_size,
                              hipStream_t stream) {
    const float* hs     = (const float*)d_in[0];
    const float* wq     = (const float*)d_in[1];
    const float* wkv_a  = (const float*)d_in[2];
    const float* ln_g   = (const float*)d_in[3];
    const float* ln_b   = (const float*)d_in[4];
    const float* wkv_b  = (const float*)d_in[5];
    const float* wo     = (const float*)d_in[6];
    const float* fc_c_w = (const float*)d_in[7];
    const float* fc_c_b = (const float*)d_in[8];
    const float* fc_p_w = (const float*)d_in[9];
    const float* fc_p_b = (const float*)d_in[10];
    float* out = (float*)d_out;
    (void)in_sizes; (void)n_in; (void)out_size; (void)ws_size;

    const int M = B_ * S_;  // 4096
    char* wsb = (char*)d_ws;
    size_t o = 0;
    auto alloc = [&](size_t bytes) { char* p = wsb + o; o += (bytes + 255) & ~(size_t)255; return p; };

    bf16* qe = (bf16*)alloc((size_t)M * H_ * 288 * 2);  // 37.75 MB
    char* region2 = alloc((size_t)M * H_ * 256 * 2);    // 33.55 MB
    bf16* hs_bf    = (bf16*)region2;
    bf16* wq_bf    = (bf16*)(region2 + (size_t)M * E_ * 2);
    bf16* wkva_pad = (bf16*)(region2 + (size_t)M * E_ * 2 + (size_t)1536 * E_ * 2);
    bf16* x_bf     = (bf16*)region2;
    char* region3 = alloc((size_t)M * 1536 * 2);        // 12.58 MB
    bf16* q_bf    = (bf16*)region3;
    bf16* outp_bf = (bf16*)region3;
    float* kvraw = (float*)alloc((size_t)M * 384 * 4);
    float* kv_c  = (float*)alloc((size_t)M * 256 * 4);
    float* kpe   = (float*)alloc((size_t)M * 32 * 4);
    bf16* wo_bf   = (bf16*)alloc((size_t)E_ * 1024 * 2);
    bf16* wkvb_bf = (bf16*)alloc((size_t)2048 * 256 * 2);
    bf16* wkvbT   = (bf16*)alloc((size_t)H_ * 256 * 64 * 2);
    bf16* kve_full = (bf16*)alloc((size_t)M * 288 * 2);
    bf16* kvo      = (bf16*)alloc((size_t)B_ * 1024 * 296 * 2);
    bf16* kvoT     = (bf16*)alloc((size_t)B_ * 64 * 4096 * 2);
    float* C2 = (float*)alloc((size_t)S_ * 64 * 4);
    float* P2 = (float*)alloc((size_t)S_ * 64 * 4);
    float* g0 = (float*)alloc(S_ * 4);
    float* g1 = (float*)alloc(S_ * 4);

    // conversions
    conv_bf16_kernel<<<(M * E_ / 8 + 255) / 256, 256, 0, stream>>>(hs, hs_bf, M * E_ / 8);
    conv_bf16_kernel<<<(1536 * E_ / 8 + 255) / 256, 256, 0, stream>>>(wq, wq_bf, 1536 * E_ / 8);
    conv_bf16_kernel<<<(E_ * 1024 / 8 + 255) / 256, 256, 0, stream>>>(wo, wo_bf, E_ * 1024 / 8);
    conv_bf16_kernel<<<(2048 * 256 / 8 + 255) / 256, 256, 0, stream>>>(wkv_b, wkvb_bf, 2048 * 256 / 8);
    conv_pad_wkva_kernel<<<(384 * 2048 / 8 + 255) / 256, 256, 0, stream>>>(wkv_a, wkva_pad);
    transpose_wkvbT_kernel<<<H_, 256, 0, stream>>>(wkv_b, wkvbT);
    // projections (m97-style MFMA GEMM)
    gemm_bt_lds<bf16><<<dim3(1536 / 128, M / 128), 256, 0, stream>>>(hs_bf, wq_bf, q_bf, M, 1536, E_);
    gemm_bt_lds<float><<<dim3(384 / 128, M / 128), 256, 0, stream>>>(hs_bf, wkva_pad, kvraw, M, 384, E_);
    // LN + k_pe rope
    ln_rope_kernel<<<M, 256, 0, stream>>>(kvraw, ln_g, ln_b, kv_c, kpe);
    // gates
    c2p2_kernel<<<S_, 64, 0, stream>>>(fc_c_w, fc_c_b, fc_p_w, fc_p_b, C2, P2);
    gates_kernel<<<(S_ + 255) / 256, 256, 0, stream>>>(C2, P2, g0, g1);
    // kve (full + packed odd) and u-chunked transpose
    kve_kernel<<<M, 256, 0, stream>>>(kv_c, kpe, g0, g1, kve_full, kvo);
    kvoT2_kernel<<<dim3(64, B_), 256, 0, stream>>>(kvo, kvoT);
    // qe = [q_abs * SCALE | rope(q_pe) * SCALE]
    gemm64_lds<bf16><<<dim3(256 / 64, M / 64, H_), 256, 0, stream>>>(
        q_bf, H_ * QKD_, QKD_, wkvbT, 64, 256 * 64, qe, H_ * 288, 288, 64, SCALE_);
    rope_qe_kernel<<<(M * H_ * 16 + 255) / 256, 256, 0, stream>>>(q_bf, qe);
    // attention (self-score fused)
    attn4_kernel<<<dim3(S_ / 4, B_), 256, 0, stream>>>(qe, kvo, kvoT, kve_full, x_bf);
    // V-projection per head
    gemm64_lds<bf16><<<dim3(1, M / 64, H_), 256, 0, stream>>>(
        x_bf, H_ * 256, 256, wkvb_bf + (size_t)64 * 256, 256, 128 * 256, outp_bf, 1024, 64, 256, 1.0f);
    // final out = outp @ wo^T
    gemm_bt_lds<float><<<dim3(E_ / 128, M / 128), 256, 0, stream>>>(outp_bf, wo_bf, out, M, E_, 1024);
}